// Round 10
// baseline (450.326 us; speedup 1.0000x reference)
//
#include <hip/hip_runtime.h>

#define NROWS 2048
#define SLEN  1024
#define FEAT  25088
#define DFC   512
#define DG1   512
#define DG2   256
#define CSPLIT 128   // k-splits for centers partial GEMM

typedef __attribute__((ext_vector_type(8))) short short8;
typedef __attribute__((ext_vector_type(4))) float f32x4;

__device__ __forceinline__ unsigned short bfbits(float f) {
  unsigned int u = __float_as_uint(f);
  u += 0x7fffu + ((u >> 16) & 1u);   // RNE to bf16
  return (unsigned short)(u >> 16);
}

// HW packed f32->bf16 (RNE), 2 elems / instruction
__device__ __forceinline__ unsigned int cvtpk(float lo, float hi) {
  unsigned int r;
  asm("v_cvt_pk_bf16_f32 %0, %1, %2" : "=v"(r) : "v"(lo), "v"(hi));
  return r;
}

// async global->LDS, 16B per lane; lds base must be wave-uniform (HW adds lane*16)
__device__ __forceinline__ void load_lds16(const void* g, void* l) {
  __builtin_amdgcn_global_load_lds(
      (const __attribute__((address_space(1))) unsigned int*)g,
      (__attribute__((address_space(3))) unsigned int*)l, 16, 0, 0);
}

// ---------- fused: x fp32 -> bf16 (all rows) + per-class source partial sums ----------
__global__ void convert_segsum_k(const float* __restrict__ x, const int* __restrict__ slab,
                                 unsigned short* __restrict__ xbf, float* __restrict__ sxp) {
  int k4 = blockIdx.x * 256 + threadIdx.x;
  if (k4 >= FEAT / 4) return;
  int k = k4 * 4;
  int i0 = blockIdx.y * 64, i1 = i0 + 64;
  bool src = blockIdx.y < 16;
  float4 a0 = {0,0,0,0}, a1 = {0,0,0,0}, a2 = {0,0,0,0}, a3 = {0,0,0,0};
  #pragma unroll 4
  for (int i = i0; i < i1; i++) {
    float4 v = *reinterpret_cast<const float4*>(x + (size_t)i * FEAT + k);
    uint2 st;
    st.x = cvtpk(v.x, v.y);
    st.y = cvtpk(v.z, v.w);
    *reinterpret_cast<uint2*>(xbf + (size_t)i * FEAT + k) = st;
    if (src) {
      int c = slab[i];
      float m0 = (c == 0) ? 1.f : 0.f, m1 = (c == 1) ? 1.f : 0.f;
      float m2 = (c == 2) ? 1.f : 0.f, m3 = (c == 3) ? 1.f : 0.f;
      a0.x += m0 * v.x; a0.y += m0 * v.y; a0.z += m0 * v.z; a0.w += m0 * v.w;
      a1.x += m1 * v.x; a1.y += m1 * v.y; a1.z += m1 * v.z; a1.w += m1 * v.w;
      a2.x += m2 * v.x; a2.y += m2 * v.y; a2.z += m2 * v.z; a2.w += m2 * v.w;
      a3.x += m3 * v.x; a3.y += m3 * v.y; a3.z += m3 * v.z; a3.w += m3 * v.w;
    }
  }
  if (src) {
    size_t base = (size_t)blockIdx.y * 4 * FEAT;
    *reinterpret_cast<float4*>(sxp + base + 0 * FEAT + k) = a0;
    *reinterpret_cast<float4*>(sxp + base + 1 * FEAT + k) = a1;
    *reinterpret_cast<float4*>(sxp + base + 2 * FEAT + k) = a2;
    *reinterpret_cast<float4*>(sxp + base + 3 * FEAT + k) = a3;
  }
}

// ---------- transpose fp32 [K][N] -> bf16 [N][K] ----------
__global__ void transpose_cvt_k(const float* __restrict__ src, unsigned short* __restrict__ dst,
                                int K, int Ncol) {
  __shared__ float tile[64][65];
  int kb = blockIdx.x * 64, nb = blockIdx.y * 64;
  int tx = threadIdx.x & 63, ty = threadIdx.x >> 6;
  #pragma unroll
  for (int i = ty; i < 64; i += 4)
    tile[i][tx] = src[(size_t)(kb + i) * Ncol + (nb + tx)];
  __syncthreads();
  #pragma unroll
  for (int i = ty; i < 64; i += 4)
    dst[(size_t)(nb + i) * K + (kb + tx)] = bfbits(tile[tx][i]);
}

// ---------- FC 256x256 bf16 GEMM: BK=32, dbuf, 2-barrier, 512 thr (8 waves 4m x 2n) ----------
// Traffic-halved vs 128^2: A x2 + B x8 = 412 MB L2-side. LDS 64 KB -> with
// splitK 32 (uneven 25/24 steps) grid = 512 blocks = 2 blocks/CU, so barrier
// drains overlap across co-resident blocks (m114). Zero-conflict swizzle
// family p = c ^ ((r>>1)&3) (measured 0 conflicts in R5/R6).
__global__ __launch_bounds__(512, 2) void gemm_fc256_k(const unsigned short* __restrict__ A,
    const unsigned short* __restrict__ BT, float* __restrict__ Cacc) {
  __shared__ unsigned short Al[2][256 * 32];  // 2 x 16 KB
  __shared__ unsigned short Bl[2][256 * 32];  // 2 x 16 KB
  const int K = FEAT;
  int tid = threadIdx.x;
  int m0 = (blockIdx.x >> 1) * 256;           // 8 m-tiles
  int n0 = (blockIdx.x & 1) * 256;            // 2 n-tiles
  int y = blockIdx.y;                          // 32 k-splits, uneven: y<16 -> 25 steps
  int ksteps = 24 + (y < 16 ? 1 : 0);
  int kbase = (y * 24 + (y < 16 ? y : 16)) * 32;
  int wid = tid >> 6, lane = tid & 63;
  int wm = wid >> 1, wn = wid & 1;            // wave = 64 rows x 128 cols
  int lrow = lane & 15, lko = lane >> 4;

  f32x4 acc[4][8];
  #pragma unroll
  for (int i = 0; i < 4; i++)
    #pragma unroll
    for (int j = 0; j < 8; j++) acc[i][j] = (f32x4){0.f, 0.f, 0.f, 0.f};

  auto stage = [&](unsigned short (*L)[256 * 32], const unsigned short* G, int buf, int k0) {
    #pragma unroll
    for (int j = 0; j < 2; j++) {
      int chb = j * 512 + wid * 64;           // wave-uniform base chunk
      int ch = chb + lane;                    // 1024 chunks: r = ch>>2 (0..255), p = ch&3
      int r = ch >> 2, p = ch & 3;
      int c = p ^ ((r >> 1) & 3);             // inverse-swizzled global col
      load_lds16(G + (size_t)r * K + k0 + c * 8, (char*)L[buf] + chb * 16);
    }
  };

  stage(Al, A + (size_t)m0 * K, 0, kbase);
  stage(Bl, BT + (size_t)n0 * K, 0, kbase);
  __syncthreads();

  int cur = 0;
  for (int t = 0; t < ksteps; ++t) {
    if (t + 1 < ksteps) {
      stage(Al, A + (size_t)m0 * K, cur ^ 1, kbase + (t + 1) * 32);
      stage(Bl, BT + (size_t)n0 * K, cur ^ 1, kbase + (t + 1) * 32);
    }
    short8 af[4], bf8[8];
    #pragma unroll
    for (int mi = 0; mi < 4; mi++) {
      int R = wm * 64 + mi * 16 + lrow;
      int p = lko ^ ((R >> 1) & 3);
      af[mi] = *reinterpret_cast<const short8*>((char*)Al[cur] + R * 64 + p * 16);
    }
    #pragma unroll
    for (int ni = 0; ni < 8; ni++) {
      int R = wn * 128 + ni * 16 + lrow;
      int p = lko ^ ((R >> 1) & 3);
      bf8[ni] = *reinterpret_cast<const short8*>((char*)Bl[cur] + R * 64 + p * 16);
    }
    #pragma unroll
    for (int mi = 0; mi < 4; mi++)
      #pragma unroll
      for (int ni = 0; ni < 8; ni++)
        acc[mi][ni] = __builtin_amdgcn_mfma_f32_16x16x32_bf16(af[mi], bf8[ni], acc[mi][ni], 0, 0, 0);
    __syncthreads();   // drains gload_lds (cur^1) + readers of cur
    cur ^= 1;
  }

  #pragma unroll
  for (int mi = 0; mi < 4; mi++)
    #pragma unroll
    for (int ni = 0; ni < 8; ni++)
      #pragma unroll
      for (int r = 0; r < 4; r++) {
        int row = m0 + wm * 64 + mi * 16 + lko * 4 + r;   // C/D: row=(lane>>4)*4+r
        int col = n0 + wn * 128 + ni * 16 + lrow;         //      col=lane&15
        atomicAdd(&Cacc[(size_t)row * DFC + col], acc[mi][ni][r]);
      }
}

// ---------- FALLBACK FC GEMM (R4-proven): 256x256, BK=32, depth-2 counted vmcnt ----------
__global__ __launch_bounds__(512, 2) void gemm_fc_k(const float* __restrict__ A,
    const unsigned short* __restrict__ BT, float* __restrict__ Cacc, int ksteps) {
  __shared__ unsigned short Al[2][256 * 32];  // 2 x 16 KB
  __shared__ unsigned short Bl[2][256 * 32];  // 2 x 16 KB
  const int K = FEAT;
  int tid = threadIdx.x;
  int m0 = (blockIdx.x >> 1) * 256;
  int n0 = (blockIdx.x & 1) * 256;
  int kbase = blockIdx.y * ksteps * 32;
  int wid = tid >> 6, lane = tid & 63;
  int wm = wid >> 1, wn = wid & 1;            // 4 x 2 waves; wave = 64 rows x 128 cols
  int lrow = lane & 15, lko = lane >> 4;

  f32x4 acc[4][8];
  #pragma unroll
  for (int i = 0; i < 4; i++)
    #pragma unroll
    for (int j = 0; j < 8; j++) acc[i][j] = (f32x4){0.f, 0.f, 0.f, 0.f};

  float4 pa[4];

  auto loadA_regs = [&](int k0) {
    #pragma unroll
    for (int j = 0; j < 2; j++) {
      int ch = tid + j * 512;
      int r = ch >> 2, c = ch & 3;
      const float* g = A + (size_t)(m0 + r) * K + k0 + c * 8;
      pa[2 * j]     = *reinterpret_cast<const float4*>(g);
      pa[2 * j + 1] = *reinterpret_cast<const float4*>(g + 4);
    }
  };
  auto cvtWriteA = [&](int buf) {
    #pragma unroll
    for (int j = 0; j < 2; j++) {
      int ch = tid + j * 512;
      int r = ch >> 2, c = ch & 3;
      int p = c ^ (r & 3);
      int4 o;
      o.x = (int)cvtpk(pa[2 * j].x,     pa[2 * j].y);
      o.y = (int)cvtpk(pa[2 * j].z,     pa[2 * j].w);
      o.z = (int)cvtpk(pa[2 * j + 1].x, pa[2 * j + 1].y);
      o.w = (int)cvtpk(pa[2 * j + 1].z, pa[2 * j + 1].w);
      *reinterpret_cast<int4*>((char*)Al[buf] + r * 64 + p * 16) = o;
    }
  };
  auto stageB = [&](int buf, int k0) {
    #pragma unroll
    for (int j = 0; j < 2; j++) {
      int chb = wid * 128 + j * 64;
      int ch = chb + lane;
      int r = ch >> 2, c = (ch & 3) ^ (r & 3);
      load_lds16(BT + (size_t)(n0 + r) * K + k0 + c * 8, (char*)Bl[buf] + chb * 16);
    }
  };

  loadA_regs(kbase);
  stageB(0, kbase);
  cvtWriteA(0);
  loadA_regs(kbase + 32);
  stageB(1, kbase + 32);
  asm volatile("s_waitcnt vmcnt(6)" ::: "memory");
  asm volatile("s_waitcnt lgkmcnt(0)" ::: "memory");
  __builtin_amdgcn_s_barrier();
  __builtin_amdgcn_sched_barrier(0);

  int cur = 0;
  for (int t = 0; t < ksteps; ++t) {
    bool more1 = (t + 1 < ksteps), more2 = (t + 2 < ksteps);
    if (more1) cvtWriteA(cur ^ 1);
    short8 af[4], bf8[8];
    #pragma unroll
    for (int mi = 0; mi < 4; mi++) {
      int R = wm * 64 + mi * 16 + lrow;
      int p = lko ^ (R & 3);
      af[mi] = *reinterpret_cast<const short8*>((char*)Al[cur] + R * 64 + p * 16);
    }
    #pragma unroll
    for (int ni = 0; ni < 8; ni++) {
      int R = wn * 128 + ni * 16 + lrow;
      int p = lko ^ (R & 3);
      bf8[ni] = *reinterpret_cast<const short8*>((char*)Bl[cur] + R * 64 + p * 16);
    }
    if (more2) loadA_regs(kbase + (t + 2) * 32);
    asm volatile("s_waitcnt lgkmcnt(0)" ::: "memory");
    __builtin_amdgcn_s_barrier();
    __builtin_amdgcn_sched_barrier(0);
    if (more2) stageB(cur, kbase + (t + 2) * 32);
    #pragma unroll
    for (int mi = 0; mi < 4; mi++)
      #pragma unroll
      for (int ni = 0; ni < 8; ni++)
        acc[mi][ni] = __builtin_amdgcn_mfma_f32_16x16x32_bf16(af[mi], bf8[ni], acc[mi][ni], 0, 0, 0);
    if (more1) {
      if (more2) { asm volatile("s_waitcnt vmcnt(6)" ::: "memory"); }
      else       { asm volatile("s_waitcnt vmcnt(0)" ::: "memory"); }
      __builtin_amdgcn_sched_barrier(0);
    }
    cur ^= 1;
  }

  #pragma unroll
  for (int mi = 0; mi < 4; mi++)
    #pragma unroll
    for (int ni = 0; ni < 8; ni++)
      #pragma unroll
      for (int r = 0; r < 4; r++) {
        int row = m0 + wm * 64 + mi * 16 + lko * 4 + r;
        int col = n0 + wn * 128 + ni * 16 + lrow;
        atomicAdd(&Cacc[(size_t)row * DFC + col], acc[mi][ni][r]);
      }
}

// ---------- bf16 MFMA GEMM: 128x128 tile, BK=64, dbuf (layer GEMMs) ----------
__global__ __launch_bounds__(256) void gemm_l_k(const unsigned short* __restrict__ A,
    const unsigned short* __restrict__ BT, float* __restrict__ Cacc,
    int K, int Ncols, int tiles_n, int ksteps) {
  __shared__ unsigned short Al[2][128 * 64];
  __shared__ unsigned short Bl[2][128 * 64];
  int tid = threadIdx.x;
  int m0 = (blockIdx.x / tiles_n) * 128;
  int n0 = (blockIdx.x % tiles_n) * 128;
  int kbase = blockIdx.y * ksteps * 64;
  int wid = tid >> 6, lane = tid & 63;
  int wm = wid >> 1, wn = wid & 1;
  int lrow = lane & 15, lko = lane >> 4;

  f32x4 acc[4][4];
  #pragma unroll
  for (int i = 0; i < 4; i++)
    #pragma unroll
    for (int j = 0; j < 4; j++) acc[i][j] = (f32x4){0.f, 0.f, 0.f, 0.f};

  auto stage = [&](unsigned short (*L)[128 * 64], const unsigned short* G, int buf, int k0) {
    #pragma unroll
    for (int j = 0; j < 4; j++) {
      int chb = j * 256 + wid * 64;
      int ch = chb + lane;
      int r = ch >> 3, c = (ch & 7) ^ (r & 7);
      load_lds16(G + (size_t)r * K + k0 + c * 8, (char*)L[buf] + chb * 16);
    }
  };

  stage(Al, A + (size_t)m0 * K, 0, kbase);
  stage(Bl, BT + (size_t)n0 * K, 0, kbase);
  __syncthreads();

  int cur = 0;
  for (int t = 0; t < ksteps; ++t) {
    bool more = (t + 1 < ksteps);
    if (more) {
      stage(Al, A + (size_t)m0 * K, cur ^ 1, kbase + (t + 1) * 64);
      stage(Bl, BT + (size_t)n0 * K, cur ^ 1, kbase + (t + 1) * 64);
    }
    #pragma unroll
    for (int kk = 0; kk < 2; kk++) {
      short8 af[4], bfv[4];
      #pragma unroll
      for (int mi = 0; mi < 4; mi++) {
        int R = wm * 64 + mi * 16 + lrow;
        int slot = ((kk << 2) | lko) ^ (lrow & 7);
        af[mi] = *reinterpret_cast<const short8*>((char*)Al[cur] + R * 128 + slot * 16);
      }
      #pragma unroll
      for (int ni = 0; ni < 4; ni++) {
        int R = wn * 64 + ni * 16 + lrow;
        int slot = ((kk << 2) | lko) ^ (lrow & 7);
        bfv[ni] = *reinterpret_cast<const short8*>((char*)Bl[cur] + R * 128 + slot * 16);
      }
      #pragma unroll
      for (int mi = 0; mi < 4; mi++)
        #pragma unroll
        for (int ni = 0; ni < 4; ni++)
          acc[mi][ni] = __builtin_amdgcn_mfma_f32_16x16x32_bf16(af[mi], bfv[ni], acc[mi][ni], 0, 0, 0);
    }
    __syncthreads();
    cur ^= 1;
  }
  #pragma unroll
  for (int mi = 0; mi < 4; mi++)
    #pragma unroll
    for (int ni = 0; ni < 4; ni++)
      #pragma unroll
      for (int r = 0; r < 4; r++) {
        int row = m0 + wm * 64 + mi * 16 + lko * 4 + r;
        int col = n0 + wn * 64 + ni * 16 + lrow;
        atomicAdd(&Cacc[(size_t)row * Ncols + col], acc[mi][ni][r]);
      }
}

// ---------- feats finalize: +bias -> fp32 out + bf16 copy ----------
__global__ void feats_fin_k(const float* __restrict__ facc, const float* __restrict__ bfc,
                            float* __restrict__ outf, unsigned short* __restrict__ outbf) {
  int i = blockIdx.y;
  int n = blockIdx.x * 256 + threadIdx.x;
  float v = facc[(size_t)i * DFC + n] + bfc[n];
  outf[(size_t)i * DFC + n] = v;
  outbf[(size_t)i * DFC + n] = bfbits(v);
}

// ---------- exact label path (fallback stage-1; xbf path uses convert_segsum_k) ----------
__global__ void seg_sum_part_k(const float* __restrict__ x, const int* __restrict__ slab,
                               float* __restrict__ sxp) {
  int k4 = blockIdx.x * 256 + threadIdx.x;
  if (k4 >= FEAT / 4) return;
  int k = k4 * 4;
  int i0 = blockIdx.y * 64, i1 = i0 + 64;
  float4 a0 = {0,0,0,0}, a1 = {0,0,0,0}, a2 = {0,0,0,0}, a3 = {0,0,0,0};
  #pragma unroll 4
  for (int i = i0; i < i1; i++) {
    float4 v = *reinterpret_cast<const float4*>(x + (size_t)i * FEAT + k);
    int c = slab[i];
    float m0 = (c == 0) ? 1.f : 0.f, m1 = (c == 1) ? 1.f : 0.f;
    float m2 = (c == 2) ? 1.f : 0.f, m3 = (c == 3) ? 1.f : 0.f;
    a0.x += m0 * v.x; a0.y += m0 * v.y; a0.z += m0 * v.z; a0.w += m0 * v.w;
    a1.x += m1 * v.x; a1.y += m1 * v.y; a1.z += m1 * v.z; a1.w += m1 * v.w;
    a2.x += m2 * v.x; a2.y += m2 * v.y; a2.z += m2 * v.z; a2.w += m2 * v.w;
    a3.x += m3 * v.x; a3.y += m3 * v.y; a3.z += m3 * v.z; a3.w += m3 * v.w;
  }
  size_t base = (size_t)blockIdx.y * 4 * FEAT;
  *reinterpret_cast<float4*>(sxp + base + 0 * FEAT + k) = a0;
  *reinterpret_cast<float4*>(sxp + base + 1 * FEAT + k) = a1;
  *reinterpret_cast<float4*>(sxp + base + 2 * FEAT + k) = a2;
  *reinterpret_cast<float4*>(sxp + base + 3 * FEAT + k) = a3;
}

__global__ void seg_sum_reduce_k(const float* __restrict__ sxp, float* __restrict__ sx) {
  int k4 = blockIdx.x * 256 + threadIdx.x;
  if (k4 >= FEAT / 4) return;
  int k = k4 * 4;
  int c = blockIdx.y;
  double s0 = 0, s1 = 0, s2 = 0, s3 = 0;
  #pragma unroll
  for (int p = 0; p < 16; p++) {
    float4 v = *reinterpret_cast<const float4*>(sxp + ((size_t)p * 4 + c) * FEAT + k);
    s0 += (double)v.x; s1 += (double)v.y; s2 += (double)v.z; s3 += (double)v.w;
  }
  float4 r; r.x = (float)s0; r.y = (float)s1; r.z = (float)s2; r.w = (float)s3;
  *reinterpret_cast<float4*>(sx + (size_t)c * FEAT + k) = r;
}

__global__ void count_src_k(const int* __restrict__ slab, int* __restrict__ cnt) {
  __shared__ int c[4];
  if (threadIdx.x < 4) c[threadIdx.x] = 0;
  __syncthreads();
  for (int i = threadIdx.x; i < SLEN; i += 256) atomicAdd(&c[slab[i]], 1);
  __syncthreads();
  if (threadIdx.x < 4) cnt[threadIdx.x] = c[threadIdx.x];
}

__global__ void centers_part_k(const float* __restrict__ sx, const float* __restrict__ W,
                               double* __restrict__ cpart) {
  int n = blockIdx.x * 64 + (threadIdx.x & 63);
  int cc = threadIdx.x >> 6;
  int kb = blockIdx.y * (FEAT / CSPLIT), ke = kb + FEAT / CSPLIT;
  const float* sr = sx + (size_t)cc * FEAT;
  double acc = 0.0;
  #pragma unroll 4
  for (int k = kb; k < ke; k++)
    acc += (double)sr[k] * (double)W[(size_t)k * DFC + n];
  cpart[((size_t)blockIdx.y * 4 + cc) * DFC + n] = acc;
}

__global__ void centers_reduce_k(const double* __restrict__ cpart, const float* __restrict__ bfc,
                                 const int* __restrict__ cntsrc, float* __restrict__ Cent) {
  int idx = blockIdx.x * 256 + threadIdx.x;
  int cc = idx >> 9, n = idx & 511;
  double s = 0.0;
  #pragma unroll 4
  for (int p = 0; p < CSPLIT; p++) s += cpart[((size_t)p * 4 + cc) * DFC + n];
  Cent[idx] = (float)(s + (double)cntsrc[cc] * (double)bfc[n]);
}

__global__ void wc_k(const float* __restrict__ W, const float* __restrict__ Cent,
                     float* __restrict__ wc) {
  __shared__ float cs[4 * DFC];
  for (int i = threadIdx.x; i < 4 * DFC; i += 256) cs[i] = Cent[i];
  __syncthreads();
  int k = blockIdx.x * 256 + threadIdx.x;
  if (k >= FEAT) return;
  const float* wr = W + (size_t)k * DFC;
  double a0 = 0, a1 = 0, a2 = 0, a3 = 0;
  #pragma unroll 2
  for (int n = 0; n < DFC; n += 4) {
    float4 w4 = *reinterpret_cast<const float4*>(wr + n);
    a0 += (double)w4.x * cs[0 * DFC + n] + (double)w4.y * cs[0 * DFC + n + 1]
        + (double)w4.z * cs[0 * DFC + n + 2] + (double)w4.w * cs[0 * DFC + n + 3];
    a1 += (double)w4.x * cs[1 * DFC + n] + (double)w4.y * cs[1 * DFC + n + 1]
        + (double)w4.z * cs[1 * DFC + n + 2] + (double)w4.w * cs[1 * DFC + n + 3];
    a2 += (double)w4.x * cs[2 * DFC + n] + (double)w4.y * cs[2 * DFC + n + 1]
        + (double)w4.z * cs[2 * DFC + n + 2] + (double)w4.w * cs[2 * DFC + n + 3];
    a3 += (double)w4.x * cs[3 * DFC + n] + (double)w4.y * cs[3 * DFC + n + 1]
        + (double)w4.z * cs[3 * DFC + n + 2] + (double)w4.w * cs[3 * DFC + n + 3];
  }
  float4 r; r.x = (float)a0; r.y = (float)a1; r.z = (float)a2; r.w = (float)a3;
  *reinterpret_cast<float4*>(wc + 4 * (size_t)k) = r;
}

__global__ void kj_k(const float* __restrict__ Cent, const float* __restrict__ bfc,
                     float* __restrict__ Kj) {
  int j = threadIdx.x >> 6, lane = threadIdx.x & 63;
  float cn = 0.f, bc = 0.f;
  for (int n = lane; n < DFC; n += 64) {
    float c = Cent[j * DFC + n];
    cn += c * c; bc += bfc[n] * c;
  }
  #pragma unroll
  for (int m = 32; m >= 1; m >>= 1) { cn += __shfl_xor(cn, m); bc += __shfl_xor(bc, m); }
  if (lane == 0) Kj[j] = cn - 2.f * bc;
}

__global__ void d2_labels_k(const float* __restrict__ x, const float* __restrict__ wc,
                            const float* __restrict__ Kj, int* __restrict__ tlab) {
  int row = blockIdx.x;
  int tid = threadIdx.x;
  const float* xr = x + (size_t)(SLEN + row) * FEAT;
  double a0 = 0, a1 = 0, a2 = 0, a3 = 0;
  #pragma unroll 2
  for (int k = tid; k < FEAT; k += 256) {
    float xv = xr[k];
    float4 w4 = *reinterpret_cast<const float4*>(wc + 4 * (size_t)k);
    a0 += (double)xv * w4.x; a1 += (double)xv * w4.y;
    a2 += (double)xv * w4.z; a3 += (double)xv * w4.w;
  }
  #pragma unroll
  for (int m = 32; m >= 1; m >>= 1) {
    a0 += __shfl_xor(a0, m); a1 += __shfl_xor(a1, m);
    a2 += __shfl_xor(a2, m); a3 += __shfl_xor(a3, m);
  }
  __shared__ double s[4][4];
  int wid = tid >> 6, lane = tid & 63;
  if (lane == 0) { s[wid][0] = a0; s[wid][1] = a1; s[wid][2] = a2; s[wid][3] = a3; }
  __syncthreads();
  if (tid == 0) {
    double t0 = s[0][0] + s[1][0] + s[2][0] + s[3][0];
    double t1 = s[0][1] + s[1][1] + s[2][1] + s[3][1];
    double t2 = s[0][2] + s[1][2] + s[2][2] + s[3][2];
    double t3 = s[0][3] + s[1][3] + s[2][3] + s[3][3];
    double s0 = (double)Kj[0] - 2.0 * t0;
    double s1 = (double)Kj[1] - 2.0 * t1;
    double s2 = (double)Kj[2] - 2.0 * t2;
    double s3 = (double)Kj[3] - 2.0 * t3;
    int bi = 0; double b = s0;
    if (s1 < b) { b = s1; bi = 1; }
    if (s2 < b) { b = s2; bi = 2; }
    if (s3 < b) { b = s3; bi = 3; }
    tlab[row] = bi;
  }
}

__global__ void finalize_labels_k(const int* __restrict__ slab, const int* __restrict__ tlab,
                                  const int* __restrict__ cntsrc, int* __restrict__ alllab,
                                  float* __restrict__ dinv) {
  __shared__ int ct[4];
  if (threadIdx.x < 4) ct[threadIdx.x] = 0;
  __syncthreads();
  for (int i = threadIdx.x; i < SLEN; i += 256) atomicAdd(&ct[tlab[i]], 1);
  __syncthreads();
  for (int i = threadIdx.x; i < NROWS; i += 256) {
    int lab = (i < SLEN) ? slab[i] : tlab[i - SLEN];
    alllab[i] = lab;
    float rs = (i < SLEN) ? (2.f + (float)ct[lab])
                          : (1.f + (float)cntsrc[lab] + (float)ct[lab]);
    dinv[i] = 1.f / sqrtf(rs);
  }
}

// ---------- A_norm dense write (float4) ----------
__global__ void anorm_k(const int* __restrict__ alllab, const float* __restrict__ dinv,
                        float* __restrict__ Aout) {
  int i = blockIdx.y;
  int j0 = (blockIdx.x * 256 + threadIdx.x) * 4;
  int li = alllab[i];
  float di = dinv[i];
  int4 lj = *reinterpret_cast<const int4*>(alllab + j0);
  float4 dj = *reinterpret_cast<const float4*>(dinv + j0);
  int jj[4] = {lj.x, lj.y, lj.z, lj.w};
  float dd[4] = {dj.x, dj.y, dj.z, dj.w};
  float4 o;
  float* op = &o.x;
  #pragma unroll
  for (int e = 0; e < 4; e++) {
    int j = j0 + e;
    float v;
    if (i == j) v = 2.f * di * dd[e];
    else if (i < SLEN && j < SLEN) v = 0.f;
    else v = (li == jj[e]) ? di * dd[e] : 0.f;
    op[e] = v;
  }
  *reinterpret_cast<float4*>(Aout + (size_t)i * NROWS + j0) = o;
}

// ---------- propagation ----------
__global__ void reduce_st_k(const float* __restrict__ Xacc, const int* __restrict__ alllab,
                            const float* __restrict__ dinv, float* __restrict__ ST, int D) {
  int n = blockIdx.x * 256 + threadIdx.x;
  int i0 = blockIdx.y * 32, i1 = i0 + 32;
  float s[4] = {0, 0, 0, 0}, tt[4] = {0, 0, 0, 0};
  for (int i = i0; i < i1; ++i) {
    float v = dinv[i] * Xacc[(size_t)i * D + n];
    int lab = alllab[i];
    bool src = i < SLEN;
    #pragma unroll
    for (int c = 0; c < 4; c++) {
      s[c]  += (src && lab == c) ? v : 0.f;
      tt[c] += (!src && lab == c) ? v : 0.f;
    }
  }
  #pragma unroll
  for (int c = 0; c < 4; c++) {
    atomicAdd(&ST[c * D + n], s[c]);
    atomicAdd(&ST[(4 + c) * D + n], tt[c]);
  }
}

__global__ void apply_prop_k(const float* __restrict__ Xacc, const float* __restrict__ ST,
                             const int* __restrict__ alllab, const float* __restrict__ dinv,
                             const float* __restrict__ bias, float* __restrict__ outf,
                             unsigned short* __restrict__ outbf, int D) {
  int i = blockIdx.y;
  int n = blockIdx.x * 256 + threadIdx.x;
  float dv = dinv[i];
  int lab = alllab[i];
  float xv = Xacc[(size_t)i * D + n];
  float z;
  if (i < SLEN) z = dv * (2.f * dv * xv + ST[(4 + lab) * D + n]);
  else          z = dv * (ST[lab * D + n] + ST[(4 + lab) * D + n] + dv * xv);
  z += bias[n];
  z = fmaxf(z, 0.f);
  if (outf)  outf[(size_t)i * D + n] = z;
  if (outbf) outbf[(size_t)i * D + n] = bfbits(z);
}

extern "C" void kernel_launch(void* const* d_in, const int* in_sizes, int n_in,
                              void* d_out, int out_size, void* d_ws, size_t ws_size,
                              hipStream_t stream) {
  const float* x    = (const float*)d_in[0];
  const float* Wfc  = (const float*)d_in[1];
  const float* bfc  = (const float*)d_in[2];
  const float* Wg1  = (const float*)d_in[3];
  const float* bg1  = (const float*)d_in[4];
  const float* Wg2  = (const float*)d_in[5];
  const float* bg2  = (const float*)d_in[6];
  const int*   slab = (const int*)d_in[7];

  float* out = (float*)d_out;
  float* out_h = out;                       // 2048*256
  float* out_A = out + 524288;              // 2048*2048
  float* out_f = out + 4718592;             // 2048*512

  char* w = (char*)d_ws;
  unsigned short* wT   = (unsigned short*)(w);
  unsigned short* g1T  = (unsigned short*)(w + 25690112);
  unsigned short* g2T  = (unsigned short*)(w + 26214400);
  float* facc          = (float*)(w + 26476544);
  unsigned short* fbf  = (unsigned short*)(w + 30670848);
  float* x1acc         = (float*)(w + 32768000);
  unsigned short* h1bf = (unsigned short*)(w + 36962304);
  float* x2acc         = (float*)(w + 39059456);
  float* sx            = (float*)(w + 41156608);
  float* Cent          = (float*)(w + 41623552);
  float* wc            = (float*)(w + 41631744);
  float* Kj            = (float*)(w + 42033152);
  int*   tlab          = (int*)(w + 42033216);
  int*   alllab        = (int*)(w + 42037312);
  float* dinv          = (float*)(w + 42045504);
  int*   cntsrc        = (int*)(w + 42053696);
  float* ST1           = (float*)(w + 42053760);
  float* ST2           = (float*)(w + 42070144);

  // aliased scratch (regions dead during the label phase)
  float*  sxp     = (float*)(w + 32768000);   // alias x1acc (+h1bf head), 6.42 MB
  double* cpart_d = (double*)(w + 39059456);  // alias x2acc, 2 MB

  // optional x->bf16 buffer (beyond the legacy 42 MB layout); guarded by ws_size
  const size_t XBF_OFF = 42080256;                       // 256-aligned, past ST2
  const size_t XBF_BYTES = (size_t)NROWS * FEAT * 2;     // 102,760,448
  bool use_xbf = ws_size >= XBF_OFF + XBF_BYTES;
  unsigned short* x_bf = (unsigned short*)(w + XBF_OFF);

  hipMemsetAsync(facc,  0, (size_t)NROWS * DFC * 4, stream);
  hipMemsetAsync(ST1,   0, 8 * DG1 * 4, stream);
  hipMemsetAsync(ST2,   0, 8 * DG2 * 4, stream);

  // weight transposes + bf16 convert
  transpose_cvt_k<<<dim3(FEAT / 64, DFC / 64), 256, 0, stream>>>(Wfc, wT, FEAT, DFC);
  transpose_cvt_k<<<dim3(DFC / 64, DG1 / 64), 256, 0, stream>>>(Wg1, g1T, DFC, DG1);
  transpose_cvt_k<<<dim3(DG1 / 64, DG2 / 64), 256, 0, stream>>>(Wg2, g2T, DG1, DG2);

  if (use_xbf) {
    // ONE pass over x: bf16 convert (all rows) + class partial sums (source rows).
    convert_segsum_k<<<dim3(25, 32), 256, 0, stream>>>(x, slab, x_bf, sxp);
    // FC GEMM on L3-warm x_bf: 256^2 tile (traffic-halved), BK=32, dbuf,
    // splitK 32 uneven (16x25 + 16x24 = 784 steps) -> 512 blocks (2/CU)
    gemm_fc256_k<<<dim3(16, 32), 512, 0, stream>>>(x_bf, wT, facc);
  } else {
    // fallback: R4-proven fp32-A depth-2 pipeline + separate seg_sum pass
    gemm_fc_k<<<dim3(16, 16), 512, 0, stream>>>(x, wT, facc, 49);
    seg_sum_part_k<<<dim3(25, 16), 256, 0, stream>>>(x, slab, sxp);
  }
  feats_fin_k<<<dim3(DFC / 256, NROWS), 256, 0, stream>>>(facc, bfc, out_f, fbf);

  // exact label path (fp32/f64 from x — unaffected by the bf16 copy)
  seg_sum_reduce_k<<<dim3(25, 4), 256, 0, stream>>>(sxp, sx);
  count_src_k<<<1, 256, 0, stream>>>(slab, cntsrc);
  centers_part_k<<<dim3(DFC / 64, CSPLIT), 256, 0, stream>>>(sx, Wfc, cpart_d);
  centers_reduce_k<<<dim3(4 * DFC / 256), 256, 0, stream>>>(cpart_d, bfc, cntsrc, Cent);
  wc_k<<<dim3(FEAT / 256), 256, 0, stream>>>(Wfc, Cent, wc);
  kj_k<<<1, 256, 0, stream>>>(Cent, bfc, Kj);
  d2_labels_k<<<dim3(NROWS - SLEN), 256, 0, stream>>>(x, wc, Kj, tlab);
  finalize_labels_k<<<1, 256, 0, stream>>>(slab, tlab, cntsrc, alllab, dinv);

  // A_norm dense output
  anorm_k<<<dim3(NROWS / 1024, NROWS), 256, 0, stream>>>(alllab, dinv, out_A);

  // GCN layer 1
  hipMemsetAsync(x1acc, 0, (size_t)NROWS * DG1 * 4, stream);
  gemm_l_k<<<dim3(16 * 4, 4), 256, 0, stream>>>(fbf, g1T, x1acc, DFC, DG1, 4, 2);
  reduce_st_k<<<dim3(DG1 / 256, 64), 256, 0, stream>>>(x1acc, alllab, dinv, ST1, DG1);
  apply_prop_k<<<dim3(DG1 / 256, NROWS), 256, 0, stream>>>(x1acc, ST1, alllab, dinv, bg1,
                                                           nullptr, h1bf, DG1);

  // GCN layer 2
  hipMemsetAsync(x2acc, 0, (size_t)NROWS * DG2 * 4, stream);
  gemm_l_k<<<dim3(16 * 2, 8), 256, 0, stream>>>(h1bf, g2T, x2acc, DG1, DG2, 2, 1);
  reduce_st_k<<<dim3(DG2 / 256, 64), 256, 0, stream>>>(x2acc, alllab, dinv, ST2, DG2);
  apply_prop_k<<<dim3(DG2 / 256, NROWS), 256, 0, stream>>>(x2acc, ST2, alllab, dinv, bg2,
                                                           out_h, nullptr, DG2);

  (void)in_sizes; (void)n_in; (void)out_size;
}

// Round 11
// 355.948 us; speedup vs baseline: 1.2651x; 1.2651x over previous
//
#include <hip/hip_runtime.h>

#define NROWS 2048
#define SLEN  1024
#define FEAT  25088
#define DFC   512
#define DG1   512
#define DG2   256
#define CSPLIT 128   // k-splits for centers partial GEMM

typedef __attribute__((ext_vector_type(8))) short short8;
typedef __attribute__((ext_vector_type(4))) float f32x4;

__device__ __forceinline__ unsigned short bfbits(float f) {
  unsigned int u = __float_as_uint(f);
  u += 0x7fffu + ((u >> 16) & 1u);   // RNE to bf16
  return (unsigned short)(u >> 16);
}

// HW packed f32->bf16 (RNE), 2 elems / instruction
__device__ __forceinline__ unsigned int cvtpk(float lo, float hi) {
  unsigned int r;
  asm("v_cvt_pk_bf16_f32 %0, %1, %2" : "=v"(r) : "v"(lo), "v"(hi));
  return r;
}

// async global->LDS, 16B per lane; lds base must be wave-uniform (HW adds lane*16)
__device__ __forceinline__ void load_lds16(const void* g, void* l) {
  __builtin_amdgcn_global_load_lds(
      (const __attribute__((address_space(1))) unsigned int*)g,
      (__attribute__((address_space(3))) unsigned int*)l, 16, 0, 0);
}

// ---------- transpose fp32 [K][N] -> bf16 [N][K] ----------
__global__ void transpose_cvt_k(const float* __restrict__ src, unsigned short* __restrict__ dst,
                                int K, int Ncol) {
  __shared__ float tile[64][65];
  int kb = blockIdx.x * 64, nb = blockIdx.y * 64;
  int tx = threadIdx.x & 63, ty = threadIdx.x >> 6;
  #pragma unroll
  for (int i = ty; i < 64; i += 4)
    tile[i][tx] = src[(size_t)(kb + i) * Ncol + (nb + tx)];
  __syncthreads();
  #pragma unroll
  for (int i = ty; i < 64; i += 4)
    dst[(size_t)(nb + i) * K + (kb + tx)] = bfbits(tile[tx][i]);
}

// ---------- FC MFMA GEMM: 256x256 tile, BK=32, 512 thr (8 waves 4x2) ----------
// Depth-2 pipeline, counted vmcnt (R4-proven best: 150 us, total 356.7).
__global__ __launch_bounds__(512, 2) void gemm_fc_k(const float* __restrict__ A,
    const unsigned short* __restrict__ BT, float* __restrict__ Cacc, int ksteps) {
  __shared__ unsigned short Al[2][256 * 32];  // 2 x 16 KB
  __shared__ unsigned short Bl[2][256 * 32];  // 2 x 16 KB
  const int K = FEAT;
  int tid = threadIdx.x;
  int m0 = (blockIdx.x >> 1) * 256;
  int n0 = (blockIdx.x & 1) * 256;
  int kbase = blockIdx.y * ksteps * 32;
  int wid = tid >> 6, lane = tid & 63;
  int wm = wid >> 1, wn = wid & 1;            // 4 x 2 waves; wave = 64 rows x 128 cols
  int lrow = lane & 15, lko = lane >> 4;

  f32x4 acc[4][8];
  #pragma unroll
  for (int i = 0; i < 4; i++)
    #pragma unroll
    for (int j = 0; j < 8; j++) acc[i][j] = (f32x4){0.f, 0.f, 0.f, 0.f};

  float4 pa[4];

  auto loadA_regs = [&](int k0) {
    #pragma unroll
    for (int j = 0; j < 2; j++) {
      int ch = tid + j * 512;
      int r = ch >> 2, c = ch & 3;
      const float* g = A + (size_t)(m0 + r) * K + k0 + c * 8;
      pa[2 * j]     = *reinterpret_cast<const float4*>(g);
      pa[2 * j + 1] = *reinterpret_cast<const float4*>(g + 4);
    }
  };
  auto cvtWriteA = [&](int buf) {
    #pragma unroll
    for (int j = 0; j < 2; j++) {
      int ch = tid + j * 512;
      int r = ch >> 2, c = ch & 3;
      int p = c ^ (r & 3);
      int4 o;
      o.x = (int)cvtpk(pa[2 * j].x,     pa[2 * j].y);
      o.y = (int)cvtpk(pa[2 * j].z,     pa[2 * j].w);
      o.z = (int)cvtpk(pa[2 * j + 1].x, pa[2 * j + 1].y);
      o.w = (int)cvtpk(pa[2 * j + 1].z, pa[2 * j + 1].w);
      *reinterpret_cast<int4*>((char*)Al[buf] + r * 64 + p * 16) = o;
    }
  };
  auto stageB = [&](int buf, int k0) {
    #pragma unroll
    for (int j = 0; j < 2; j++) {
      int chb = wid * 128 + j * 64;
      int ch = chb + lane;
      int r = ch >> 2, c = (ch & 3) ^ (r & 3);
      load_lds16(BT + (size_t)(n0 + r) * K + k0 + c * 8, (char*)Bl[buf] + chb * 16);
    }
  };

  loadA_regs(kbase);
  stageB(0, kbase);
  cvtWriteA(0);
  loadA_regs(kbase + 32);
  stageB(1, kbase + 32);
  asm volatile("s_waitcnt vmcnt(6)" ::: "memory");
  asm volatile("s_waitcnt lgkmcnt(0)" ::: "memory");
  __builtin_amdgcn_s_barrier();
  __builtin_amdgcn_sched_barrier(0);

  int cur = 0;
  for (int t = 0; t < ksteps; ++t) {
    bool more1 = (t + 1 < ksteps), more2 = (t + 2 < ksteps);
    if (more1) cvtWriteA(cur ^ 1);
    short8 af[4], bf8[8];
    #pragma unroll
    for (int mi = 0; mi < 4; mi++) {
      int R = wm * 64 + mi * 16 + lrow;
      int p = lko ^ (R & 3);
      af[mi] = *reinterpret_cast<const short8*>((char*)Al[cur] + R * 64 + p * 16);
    }
    #pragma unroll
    for (int ni = 0; ni < 8; ni++) {
      int R = wn * 128 + ni * 16 + lrow;
      int p = lko ^ (R & 3);
      bf8[ni] = *reinterpret_cast<const short8*>((char*)Bl[cur] + R * 64 + p * 16);
    }
    if (more2) loadA_regs(kbase + (t + 2) * 32);
    asm volatile("s_waitcnt lgkmcnt(0)" ::: "memory");
    __builtin_amdgcn_s_barrier();
    __builtin_amdgcn_sched_barrier(0);
    if (more2) stageB(cur, kbase + (t + 2) * 32);
    #pragma unroll
    for (int mi = 0; mi < 4; mi++)
      #pragma unroll
      for (int ni = 0; ni < 8; ni++)
        acc[mi][ni] = __builtin_amdgcn_mfma_f32_16x16x32_bf16(af[mi], bf8[ni], acc[mi][ni], 0, 0, 0);
    if (more1) {
      if (more2) { asm volatile("s_waitcnt vmcnt(6)" ::: "memory"); }
      else       { asm volatile("s_waitcnt vmcnt(0)" ::: "memory"); }
      __builtin_amdgcn_sched_barrier(0);
    }
    cur ^= 1;
  }

  #pragma unroll
  for (int mi = 0; mi < 4; mi++)
    #pragma unroll
    for (int ni = 0; ni < 8; ni++)
      #pragma unroll
      for (int r = 0; r < 4; r++) {
        int row = m0 + wm * 64 + mi * 16 + lko * 4 + r;   // C/D: row=(lane>>4)*4+r
        int col = n0 + wn * 128 + ni * 16 + lrow;         //      col=lane&15
        atomicAdd(&Cacc[(size_t)row * DFC + col], acc[mi][ni][r]);
      }
}

// ---------- layer MFMA GEMM (bf16 A): 128x128 tile, BK=64, dbuf ----------
__global__ __launch_bounds__(256) void gemm_l_k(const unsigned short* __restrict__ A,
    const unsigned short* __restrict__ BT, float* __restrict__ Cacc,
    int K, int Ncols, int tiles_n, int ksteps) {
  __shared__ unsigned short Al[2][128 * 64];
  __shared__ unsigned short Bl[2][128 * 64];
  int tid = threadIdx.x;
  int m0 = (blockIdx.x / tiles_n) * 128;
  int n0 = (blockIdx.x % tiles_n) * 128;
  int kbase = blockIdx.y * ksteps * 64;
  int wid = tid >> 6, lane = tid & 63;
  int wm = wid >> 1, wn = wid & 1;
  int lrow = lane & 15, lko = lane >> 4;

  f32x4 acc[4][4];
  #pragma unroll
  for (int i = 0; i < 4; i++)
    #pragma unroll
    for (int j = 0; j < 4; j++) acc[i][j] = (f32x4){0.f, 0.f, 0.f, 0.f};

  auto stage = [&](unsigned short (*L)[128 * 64], const unsigned short* G, int buf, int k0) {
    #pragma unroll
    for (int j = 0; j < 4; j++) {
      int chb = j * 256 + wid * 64;
      int ch = chb + lane;
      int r = ch >> 3, c = (ch & 7) ^ (r & 7);
      load_lds16(G + (size_t)r * K + k0 + c * 8, (char*)L[buf] + chb * 16);
    }
  };

  stage(Al, A + (size_t)m0 * K, 0, kbase);
  stage(Bl, BT + (size_t)n0 * K, 0, kbase);
  __syncthreads();

  int cur = 0;
  for (int t = 0; t < ksteps; ++t) {
    bool more = (t + 1 < ksteps);
    if (more) {
      stage(Al, A + (size_t)m0 * K, cur ^ 1, kbase + (t + 1) * 64);
      stage(Bl, BT + (size_t)n0 * K, cur ^ 1, kbase + (t + 1) * 64);
    }
    #pragma unroll
    for (int kk = 0; kk < 2; kk++) {
      short8 af[4], bfv[4];
      #pragma unroll
      for (int mi = 0; mi < 4; mi++) {
        int R = wm * 64 + mi * 16 + lrow;
        int slot = ((kk << 2) | lko) ^ (lrow & 7);
        af[mi] = *reinterpret_cast<const short8*>((char*)Al[cur] + R * 128 + slot * 16);
      }
      #pragma unroll
      for (int ni = 0; ni < 4; ni++) {
        int R = wn * 64 + ni * 16 + lrow;
        int slot = ((kk << 2) | lko) ^ (lrow & 7);
        bfv[ni] = *reinterpret_cast<const short8*>((char*)Bl[cur] + R * 128 + slot * 16);
      }
      #pragma unroll
      for (int mi = 0; mi < 4; mi++)
        #pragma unroll
        for (int ni = 0; ni < 4; ni++)
          acc[mi][ni] = __builtin_amdgcn_mfma_f32_16x16x32_bf16(af[mi], bfv[ni], acc[mi][ni], 0, 0, 0);
    }
    __syncthreads();
    cur ^= 1;
  }
  #pragma unroll
  for (int mi = 0; mi < 4; mi++)
    #pragma unroll
    for (int ni = 0; ni < 4; ni++)
      #pragma unroll
      for (int r = 0; r < 4; r++) {
        int row = m0 + wm * 64 + mi * 16 + lko * 4 + r;
        int col = n0 + wn * 64 + ni * 16 + lrow;
        atomicAdd(&Cacc[(size_t)row * Ncols + col], acc[mi][ni][r]);
      }
}

// ---------- feats finalize: +bias -> fp32 out + bf16 copy ----------
__global__ void feats_fin_k(const float* __restrict__ facc, const float* __restrict__ bfc,
                            float* __restrict__ outf, unsigned short* __restrict__ outbf) {
  int i = blockIdx.y;
  int n = blockIdx.x * 256 + threadIdx.x;
  float v = facc[(size_t)i * DFC + n] + bfc[n];
  outf[(size_t)i * DFC + n] = v;
  outbf[(size_t)i * DFC + n] = bfbits(v);
}

// ---------- exact label path ----------
__global__ void seg_sum_part_k(const float* __restrict__ x, const int* __restrict__ slab,
                               float* __restrict__ sxp) {
  int k4 = blockIdx.x * 256 + threadIdx.x;
  if (k4 >= FEAT / 4) return;
  int k = k4 * 4;
  int i0 = blockIdx.y * 64, i1 = i0 + 64;
  float4 a0 = {0,0,0,0}, a1 = {0,0,0,0}, a2 = {0,0,0,0}, a3 = {0,0,0,0};
  #pragma unroll 4
  for (int i = i0; i < i1; i++) {
    float4 v = *reinterpret_cast<const float4*>(x + (size_t)i * FEAT + k);
    int c = slab[i];
    float m0 = (c == 0) ? 1.f : 0.f, m1 = (c == 1) ? 1.f : 0.f;
    float m2 = (c == 2) ? 1.f : 0.f, m3 = (c == 3) ? 1.f : 0.f;
    a0.x += m0 * v.x; a0.y += m0 * v.y; a0.z += m0 * v.z; a0.w += m0 * v.w;
    a1.x += m1 * v.x; a1.y += m1 * v.y; a1.z += m1 * v.z; a1.w += m1 * v.w;
    a2.x += m2 * v.x; a2.y += m2 * v.y; a2.z += m2 * v.z; a2.w += m2 * v.w;
    a3.x += m3 * v.x; a3.y += m3 * v.y; a3.z += m3 * v.z; a3.w += m3 * v.w;
  }
  size_t base = (size_t)blockIdx.y * 4 * FEAT;
  *reinterpret_cast<float4*>(sxp + base + 0 * FEAT + k) = a0;
  *reinterpret_cast<float4*>(sxp + base + 1 * FEAT + k) = a1;
  *reinterpret_cast<float4*>(sxp + base + 2 * FEAT + k) = a2;
  *reinterpret_cast<float4*>(sxp + base + 3 * FEAT + k) = a3;
}

__global__ void seg_sum_reduce_k(const float* __restrict__ sxp, float* __restrict__ sx) {
  int k4 = blockIdx.x * 256 + threadIdx.x;
  if (k4 >= FEAT / 4) return;
  int k = k4 * 4;
  int c = blockIdx.y;
  double s0 = 0, s1 = 0, s2 = 0, s3 = 0;
  #pragma unroll
  for (int p = 0; p < 16; p++) {
    float4 v = *reinterpret_cast<const float4*>(sxp + ((size_t)p * 4 + c) * FEAT + k);
    s0 += (double)v.x; s1 += (double)v.y; s2 += (double)v.z; s3 += (double)v.w;
  }
  float4 r; r.x = (float)s0; r.y = (float)s1; r.z = (float)s2; r.w = (float)s3;
  *reinterpret_cast<float4*>(sx + (size_t)c * FEAT + k) = r;
}

__global__ void count_src_k(const int* __restrict__ slab, int* __restrict__ cnt) {
  __shared__ int c[4];
  if (threadIdx.x < 4) c[threadIdx.x] = 0;
  __syncthreads();
  for (int i = threadIdx.x; i < SLEN; i += 256) atomicAdd(&c[slab[i]], 1);
  __syncthreads();
  if (threadIdx.x < 4) cnt[threadIdx.x] = c[threadIdx.x];
}

__global__ void centers_part_k(const float* __restrict__ sx, const float* __restrict__ W,
                               double* __restrict__ cpart) {
  int n = blockIdx.x * 64 + (threadIdx.x & 63);
  int cc = threadIdx.x >> 6;
  int kb = blockIdx.y * (FEAT / CSPLIT), ke = kb + FEAT / CSPLIT;
  const float* sr = sx + (size_t)cc * FEAT;
  double acc = 0.0;
  #pragma unroll 4
  for (int k = kb; k < ke; k++)
    acc += (double)sr[k] * (double)W[(size_t)k * DFC + n];
  cpart[((size_t)blockIdx.y * 4 + cc) * DFC + n] = acc;
}

__global__ void centers_reduce_k(const double* __restrict__ cpart, const float* __restrict__ bfc,
                                 const int* __restrict__ cntsrc, float* __restrict__ Cent) {
  int idx = blockIdx.x * 256 + threadIdx.x;
  int cc = idx >> 9, n = idx & 511;
  double s = 0.0;
  #pragma unroll 4
  for (int p = 0; p < CSPLIT; p++) s += cpart[((size_t)p * 4 + cc) * DFC + n];
  Cent[idx] = (float)(s + (double)cntsrc[cc] * (double)bfc[n]);
}

__global__ void wc_k(const float* __restrict__ W, const float* __restrict__ Cent,
                     float* __restrict__ wc) {
  __shared__ float cs[4 * DFC];
  for (int i = threadIdx.x; i < 4 * DFC; i += 256) cs[i] = Cent[i];
  __syncthreads();
  int k = blockIdx.x * 256 + threadIdx.x;
  if (k >= FEAT) return;
  const float* wr = W + (size_t)k * DFC;
  double a0 = 0, a1 = 0, a2 = 0, a3 = 0;
  #pragma unroll 2
  for (int n = 0; n < DFC; n += 4) {
    float4 w4 = *reinterpret_cast<const float4*>(wr + n);
    a0 += (double)w4.x * cs[0 * DFC + n] + (double)w4.y * cs[0 * DFC + n + 1]
        + (double)w4.z * cs[0 * DFC + n + 2] + (double)w4.w * cs[0 * DFC + n + 3];
    a1 += (double)w4.x * cs[1 * DFC + n] + (double)w4.y * cs[1 * DFC + n + 1]
        + (double)w4.z * cs[1 * DFC + n + 2] + (double)w4.w * cs[1 * DFC + n + 3];
    a2 += (double)w4.x * cs[2 * DFC + n] + (double)w4.y * cs[2 * DFC + n + 1]
        + (double)w4.z * cs[2 * DFC + n + 2] + (double)w4.w * cs[2 * DFC + n + 3];
    a3 += (double)w4.x * cs[3 * DFC + n] + (double)w4.y * cs[3 * DFC + n + 1]
        + (double)w4.z * cs[3 * DFC + n + 2] + (double)w4.w * cs[3 * DFC + n + 3];
  }
  float4 r; r.x = (float)a0; r.y = (float)a1; r.z = (float)a2; r.w = (float)a3;
  *reinterpret_cast<float4*>(wc + 4 * (size_t)k) = r;
}

__global__ void kj_k(const float* __restrict__ Cent, const float* __restrict__ bfc,
                     float* __restrict__ Kj) {
  int j = threadIdx.x >> 6, lane = threadIdx.x & 63;
  float cn = 0.f, bc = 0.f;
  for (int n = lane; n < DFC; n += 64) {
    float c = Cent[j * DFC + n];
    cn += c * c; bc += bfc[n] * c;
  }
  #pragma unroll
  for (int m = 32; m >= 1; m >>= 1) { cn += __shfl_xor(cn, m); bc += __shfl_xor(bc, m); }
  if (lane == 0) Kj[j] = cn - 2.f * bc;
}

__global__ void d2_labels_k(const float* __restrict__ x, const float* __restrict__ wc,
                            const float* __restrict__ Kj, int* __restrict__ tlab) {
  int row = blockIdx.x;
  int tid = threadIdx.x;
  const float* xr = x + (size_t)(SLEN + row) * FEAT;
  double a0 = 0, a1 = 0, a2 = 0, a3 = 0;
  #pragma unroll 2
  for (int k = tid; k < FEAT; k += 256) {
    float xv = xr[k];
    float4 w4 = *reinterpret_cast<const float4*>(wc + 4 * (size_t)k);
    a0 += (double)xv * w4.x; a1 += (double)xv * w4.y;
    a2 += (double)xv * w4.z; a3 += (double)xv * w4.w;
  }
  #pragma unroll
  for (int m = 32; m >= 1; m >>= 1) {
    a0 += __shfl_xor(a0, m); a1 += __shfl_xor(a1, m);
    a2 += __shfl_xor(a2, m); a3 += __shfl_xor(a3, m);
  }
  __shared__ double s[4][4];
  int wid = tid >> 6, lane = tid & 63;
  if (lane == 0) { s[wid][0] = a0; s[wid][1] = a1; s[wid][2] = a2; s[wid][3] = a3; }
  __syncthreads();
  if (tid == 0) {
    double t0 = s[0][0] + s[1][0] + s[2][0] + s[3][0];
    double t1 = s[0][1] + s[1][1] + s[2][1] + s[3][1];
    double t2 = s[0][2] + s[1][2] + s[2][2] + s[3][2];
    double t3 = s[0][3] + s[1][3] + s[2][3] + s[3][3];
    double s0 = (double)Kj[0] - 2.0 * t0;
    double s1 = (double)Kj[1] - 2.0 * t1;
    double s2 = (double)Kj[2] - 2.0 * t2;
    double s3 = (double)Kj[3] - 2.0 * t3;
    int bi = 0; double b = s0;
    if (s1 < b) { b = s1; bi = 1; }
    if (s2 < b) { b = s2; bi = 2; }
    if (s3 < b) { b = s3; bi = 3; }
    tlab[row] = bi;
  }
}

__global__ void finalize_labels_k(const int* __restrict__ slab, const int* __restrict__ tlab,
                                  const int* __restrict__ cntsrc, int* __restrict__ alllab,
                                  float* __restrict__ dinv) {
  __shared__ int ct[4];
  if (threadIdx.x < 4) ct[threadIdx.x] = 0;
  __syncthreads();
  for (int i = threadIdx.x; i < SLEN; i += 256) atomicAdd(&ct[tlab[i]], 1);
  __syncthreads();
  for (int i = threadIdx.x; i < NROWS; i += 256) {
    int lab = (i < SLEN) ? slab[i] : tlab[i - SLEN];
    alllab[i] = lab;
    float rs = (i < SLEN) ? (2.f + (float)ct[lab])
                          : (1.f + (float)cntsrc[lab] + (float)ct[lab]);
    dinv[i] = 1.f / sqrtf(rs);
  }
}

// ---------- A_norm dense write (float4) ----------
__global__ void anorm_k(const int* __restrict__ alllab, const float* __restrict__ dinv,
                        float* __restrict__ Aout) {
  int i = blockIdx.y;
  int j0 = (blockIdx.x * 256 + threadIdx.x) * 4;
  int li = alllab[i];
  float di = dinv[i];
  int4 lj = *reinterpret_cast<const int4*>(alllab + j0);
  float4 dj = *reinterpret_cast<const float4*>(dinv + j0);
  int jj[4] = {lj.x, lj.y, lj.z, lj.w};
  float dd[4] = {dj.x, dj.y, dj.z, dj.w};
  float4 o;
  float* op = &o.x;
  #pragma unroll
  for (int e = 0; e < 4; e++) {
    int j = j0 + e;
    float v;
    if (i == j) v = 2.f * di * dd[e];
    else if (i < SLEN && j < SLEN) v = 0.f;
    else v = (li == jj[e]) ? di * dd[e] : 0.f;
    op[e] = v;
  }
  *reinterpret_cast<float4*>(Aout + (size_t)i * NROWS + j0) = o;
}

// ---------- propagation ----------
__global__ void reduce_st_k(const float* __restrict__ Xacc, const int* __restrict__ alllab,
                            const float* __restrict__ dinv, float* __restrict__ ST, int D) {
  int n = blockIdx.x * 256 + threadIdx.x;
  int i0 = blockIdx.y * 32, i1 = i0 + 32;
  float s[4] = {0, 0, 0, 0}, tt[4] = {0, 0, 0, 0};
  for (int i = i0; i < i1; ++i) {
    float v = dinv[i] * Xacc[(size_t)i * D + n];
    int lab = alllab[i];
    bool src = i < SLEN;
    #pragma unroll
    for (int c = 0; c < 4; c++) {
      s[c]  += (src && lab == c) ? v : 0.f;
      tt[c] += (!src && lab == c) ? v : 0.f;
    }
  }
  #pragma unroll
  for (int c = 0; c < 4; c++) {
    atomicAdd(&ST[c * D + n], s[c]);
    atomicAdd(&ST[(4 + c) * D + n], tt[c]);
  }
}

__global__ void apply_prop_k(const float* __restrict__ Xacc, const float* __restrict__ ST,
                             const int* __restrict__ alllab, const float* __restrict__ dinv,
                             const float* __restrict__ bias, float* __restrict__ outf,
                             unsigned short* __restrict__ outbf, int D) {
  int i = blockIdx.y;
  int n = blockIdx.x * 256 + threadIdx.x;
  float dv = dinv[i];
  int lab = alllab[i];
  float xv = Xacc[(size_t)i * D + n];
  float z;
  if (i < SLEN) z = dv * (2.f * dv * xv + ST[(4 + lab) * D + n]);
  else          z = dv * (ST[lab * D + n] + ST[(4 + lab) * D + n] + dv * xv);
  z += bias[n];
  z = fmaxf(z, 0.f);
  if (outf)  outf[(size_t)i * D + n] = z;
  if (outbf) outbf[(size_t)i * D + n] = bfbits(z);
}

extern "C" void kernel_launch(void* const* d_in, const int* in_sizes, int n_in,
                              void* d_out, int out_size, void* d_ws, size_t ws_size,
                              hipStream_t stream) {
  const float* x    = (const float*)d_in[0];
  const float* Wfc  = (const float*)d_in[1];
  const float* bfc  = (const float*)d_in[2];
  const float* Wg1  = (const float*)d_in[3];
  const float* bg1  = (const float*)d_in[4];
  const float* Wg2  = (const float*)d_in[5];
  const float* bg2  = (const float*)d_in[6];
  const int*   slab = (const int*)d_in[7];

  float* out = (float*)d_out;
  float* out_h = out;                       // 2048*256
  float* out_A = out + 524288;              // 2048*2048
  float* out_f = out + 4718592;             // 2048*512

  char* w = (char*)d_ws;
  unsigned short* wT   = (unsigned short*)(w);
  unsigned short* g1T  = (unsigned short*)(w + 25690112);
  unsigned short* g2T  = (unsigned short*)(w + 26214400);
  float* facc          = (float*)(w + 26476544);
  unsigned short* fbf  = (unsigned short*)(w + 30670848);
  float* x1acc         = (float*)(w + 32768000);
  unsigned short* h1bf = (unsigned short*)(w + 36962304);
  float* x2acc         = (float*)(w + 39059456);
  float* sx            = (float*)(w + 41156608);
  float* Cent          = (float*)(w + 41623552);
  float* wc            = (float*)(w + 41631744);
  float* Kj            = (float*)(w + 42033152);
  int*   tlab          = (int*)(w + 42033216);
  int*   alllab        = (int*)(w + 42037312);
  float* dinv          = (float*)(w + 42045504);
  int*   cntsrc        = (int*)(w + 42053696);
  float* ST1           = (float*)(w + 42053760);
  float* ST2           = (float*)(w + 42070144);

  // aliased scratch (regions dead during the label phase)
  float*  sxp     = (float*)(w + 32768000);   // alias x1acc (+h1bf head), 6.42 MB
  double* cpart_d = (double*)(w + 39059456);  // alias x2acc, 2 MB

  hipMemsetAsync(facc,  0, (size_t)NROWS * DFC * 4, stream);
  hipMemsetAsync(ST1,   0, 8 * DG1 * 4, stream);
  hipMemsetAsync(ST2,   0, 8 * DG2 * 4, stream);

  // weight transposes + bf16 convert
  transpose_cvt_k<<<dim3(FEAT / 64, DFC / 64), 256, 0, stream>>>(Wfc, wT, FEAT, DFC);
  transpose_cvt_k<<<dim3(DFC / 64, DG1 / 64), 256, 0, stream>>>(Wg1, g1T, DFC, DG1);
  transpose_cvt_k<<<dim3(DG1 / 64, DG2 / 64), 256, 0, stream>>>(Wg2, g2T, DG1, DG2);

  // FC GEMM: 256x256 tile, BK=32, split-K 16 (784/16 = 49 steps) -> 256 blocks
  gemm_fc_k<<<dim3(16, 16), 512, 0, stream>>>(x, wT, facc, 49);
  feats_fin_k<<<dim3(DFC / 256, NROWS), 256, 0, stream>>>(facc, bfc, out_f, fbf);

  // exact label path
  seg_sum_part_k<<<dim3(25, 16), 256, 0, stream>>>(x, slab, sxp);
  seg_sum_reduce_k<<<dim3(25, 4), 256, 0, stream>>>(sxp, sx);
  count_src_k<<<1, 256, 0, stream>>>(slab, cntsrc);
  centers_part_k<<<dim3(DFC / 64, CSPLIT), 256, 0, stream>>>(sx, Wfc, cpart_d);
  centers_reduce_k<<<dim3(4 * DFC / 256), 256, 0, stream>>>(cpart_d, bfc, cntsrc, Cent);
  wc_k<<<dim3(FEAT / 256), 256, 0, stream>>>(Wfc, Cent, wc);
  kj_k<<<1, 256, 0, stream>>>(Cent, bfc, Kj);
  d2_labels_k<<<dim3(NROWS - SLEN), 256, 0, stream>>>(x, wc, Kj, tlab);
  finalize_labels_k<<<1, 256, 0, stream>>>(slab, tlab, cntsrc, alllab, dinv);

  // A_norm dense output
  anorm_k<<<dim3(NROWS / 1024, NROWS), 256, 0, stream>>>(alllab, dinv, out_A);

  // GCN layer 1
  hipMemsetAsync(x1acc, 0, (size_t)NROWS * DG1 * 4, stream);
  gemm_l_k<<<dim3(16 * 4, 4), 256, 0, stream>>>(fbf, g1T, x1acc, DFC, DG1, 4, 2);
  reduce_st_k<<<dim3(DG1 / 256, 64), 256, 0, stream>>>(x1acc, alllab, dinv, ST1, DG1);
  apply_prop_k<<<dim3(DG1 / 256, NROWS), 256, 0, stream>>>(x1acc, ST1, alllab, dinv, bg1,
                                                           nullptr, h1bf, DG1);

  // GCN layer 2
  hipMemsetAsync(x2acc, 0, (size_t)NROWS * DG2 * 4, stream);
  gemm_l_k<<<dim3(16 * 2, 8), 256, 0, stream>>>(h1bf, g2T, x2acc, DG1, DG2, 2, 1);
  reduce_st_k<<<dim3(DG2 / 256, 64), 256, 0, stream>>>(x2acc, alllab, dinv, ST2, DG2);
  apply_prop_k<<<dim3(DG2 / 256, NROWS), 256, 0, stream>>>(x2acc, ST2, alllab, dinv, bg2,
                                                           out_h, nullptr, DG2);

  (void)in_sizes; (void)n_in; (void)out_size; (void)ws_size;
}

// Round 12
// 351.517 us; speedup vs baseline: 1.2811x; 1.0126x over previous
//
#include <hip/hip_runtime.h>

#define NROWS 2048
#define SLEN  1024
#define FEAT  25088
#define DFC   512
#define DG1   512
#define DG2   256
#define CSPLIT 128   // k-splits for centers partial GEMM

typedef __attribute__((ext_vector_type(8))) short short8;
typedef __attribute__((ext_vector_type(4))) float f32x4;

__device__ __forceinline__ unsigned short bfbits(float f) {
  unsigned int u = __float_as_uint(f);
  u += 0x7fffu + ((u >> 16) & 1u);   // RNE to bf16
  return (unsigned short)(u >> 16);
}

// HW packed f32->bf16 (RNE), 2 elems / instruction
__device__ __forceinline__ unsigned int cvtpk(float lo, float hi) {
  unsigned int r;
  asm("v_cvt_pk_bf16_f32 %0, %1, %2" : "=v"(r) : "v"(lo), "v"(hi));
  return r;
}

// async global->LDS, 16B per lane; lds base must be wave-uniform (HW adds lane*16)
__device__ __forceinline__ void load_lds16(const void* g, void* l) {
  __builtin_amdgcn_global_load_lds(
      (const __attribute__((address_space(1))) unsigned int*)g,
      (__attribute__((address_space(3))) unsigned int*)l, 16, 0, 0);
}

// ---------- transpose fp32 [K][N] -> bf16 [N][K] ----------
__global__ void transpose_cvt_k(const float* __restrict__ src, unsigned short* __restrict__ dst,
                                int K, int Ncol) {
  __shared__ float tile[64][65];
  int kb = blockIdx.x * 64, nb = blockIdx.y * 64;
  int tx = threadIdx.x & 63, ty = threadIdx.x >> 6;
  #pragma unroll
  for (int i = ty; i < 64; i += 4)
    tile[i][tx] = src[(size_t)(kb + i) * Ncol + (nb + tx)];
  __syncthreads();
  #pragma unroll
  for (int i = ty; i < 64; i += 4)
    dst[(size_t)(nb + i) * K + (kb + tx)] = bfbits(tile[tx][i]);
}

// ---------- FUSED: FC MFMA GEMM + seg_sum_part (independent, co-scheduled) ----------
// blockIdx.y < 16 : FC GEMM block (R4-proven depth-2 pipeline, unchanged).
//   256x256 tile, BK=32, 512 thr (8 waves 4x2), splitK 16.
// blockIdx.y >= 16: seg_sum block (BW-bound, rides the FC's idle ~73% HBM).
//   row-chunk = blockIdx.x (16 x 64 source rows), k-chunk = blockIdx.y-16 (13 x 512 float4).
//   Per-thread accumulation order identical to R11's seg_sum_part_k -> bit-identical sxp.
__global__ __launch_bounds__(512, 2) void gemm_fc_k(const float* __restrict__ A,
    const unsigned short* __restrict__ BT, float* __restrict__ Cacc, int ksteps,
    const int* __restrict__ slab, float* __restrict__ sxp) {
  if (blockIdx.y >= 16) {
    // ---- seg_sum_part path (A == x) ----
    int k4 = (blockIdx.y - 16) * 512 + threadIdx.x;
    if (k4 >= FEAT / 4) return;
    int k = k4 * 4;
    int i0 = blockIdx.x * 64, i1 = i0 + 64;
    float4 a0 = {0,0,0,0}, a1 = {0,0,0,0}, a2 = {0,0,0,0}, a3 = {0,0,0,0};
    #pragma unroll 4
    for (int i = i0; i < i1; i++) {
      float4 v = *reinterpret_cast<const float4*>(A + (size_t)i * FEAT + k);
      int c = slab[i];
      float m0 = (c == 0) ? 1.f : 0.f, m1 = (c == 1) ? 1.f : 0.f;
      float m2 = (c == 2) ? 1.f : 0.f, m3 = (c == 3) ? 1.f : 0.f;
      a0.x += m0 * v.x; a0.y += m0 * v.y; a0.z += m0 * v.z; a0.w += m0 * v.w;
      a1.x += m1 * v.x; a1.y += m1 * v.y; a1.z += m1 * v.z; a1.w += m1 * v.w;
      a2.x += m2 * v.x; a2.y += m2 * v.y; a2.z += m2 * v.z; a2.w += m2 * v.w;
      a3.x += m3 * v.x; a3.y += m3 * v.y; a3.z += m3 * v.z; a3.w += m3 * v.w;
    }
    size_t base = (size_t)blockIdx.x * 4 * FEAT;
    *reinterpret_cast<float4*>(sxp + base + 0 * FEAT + k) = a0;
    *reinterpret_cast<float4*>(sxp + base + 1 * FEAT + k) = a1;
    *reinterpret_cast<float4*>(sxp + base + 2 * FEAT + k) = a2;
    *reinterpret_cast<float4*>(sxp + base + 3 * FEAT + k) = a3;
    return;
  }
  // ---- FC GEMM path (byte-identical to R11) ----
  __shared__ unsigned short Al[2][256 * 32];  // 2 x 16 KB
  __shared__ unsigned short Bl[2][256 * 32];  // 2 x 16 KB
  const int K = FEAT;
  int tid = threadIdx.x;
  int m0 = (blockIdx.x >> 1) * 256;
  int n0 = (blockIdx.x & 1) * 256;
  int kbase = blockIdx.y * ksteps * 32;
  int wid = tid >> 6, lane = tid & 63;
  int wm = wid >> 1, wn = wid & 1;            // 4 x 2 waves; wave = 64 rows x 128 cols
  int lrow = lane & 15, lko = lane >> 4;

  f32x4 acc[4][8];
  #pragma unroll
  for (int i = 0; i < 4; i++)
    #pragma unroll
    for (int j = 0; j < 8; j++) acc[i][j] = (f32x4){0.f, 0.f, 0.f, 0.f};

  float4 pa[4];

  auto loadA_regs = [&](int k0) {
    #pragma unroll
    for (int j = 0; j < 2; j++) {
      int ch = tid + j * 512;
      int r = ch >> 2, c = ch & 3;
      const float* g = A + (size_t)(m0 + r) * K + k0 + c * 8;
      pa[2 * j]     = *reinterpret_cast<const float4*>(g);
      pa[2 * j + 1] = *reinterpret_cast<const float4*>(g + 4);
    }
  };
  auto cvtWriteA = [&](int buf) {
    #pragma unroll
    for (int j = 0; j < 2; j++) {
      int ch = tid + j * 512;
      int r = ch >> 2, c = ch & 3;
      int p = c ^ (r & 3);
      int4 o;
      o.x = (int)cvtpk(pa[2 * j].x,     pa[2 * j].y);
      o.y = (int)cvtpk(pa[2 * j].z,     pa[2 * j].w);
      o.z = (int)cvtpk(pa[2 * j + 1].x, pa[2 * j + 1].y);
      o.w = (int)cvtpk(pa[2 * j + 1].z, pa[2 * j + 1].w);
      *reinterpret_cast<int4*>((char*)Al[buf] + r * 64 + p * 16) = o;
    }
  };
  auto stageB = [&](int buf, int k0) {
    #pragma unroll
    for (int j = 0; j < 2; j++) {
      int chb = wid * 128 + j * 64;
      int ch = chb + lane;
      int r = ch >> 2, c = (ch & 3) ^ (r & 3);
      load_lds16(BT + (size_t)(n0 + r) * K + k0 + c * 8, (char*)Bl[buf] + chb * 16);
    }
  };

  loadA_regs(kbase);
  stageB(0, kbase);
  cvtWriteA(0);
  loadA_regs(kbase + 32);
  stageB(1, kbase + 32);
  asm volatile("s_waitcnt vmcnt(6)" ::: "memory");
  asm volatile("s_waitcnt lgkmcnt(0)" ::: "memory");
  __builtin_amdgcn_s_barrier();
  __builtin_amdgcn_sched_barrier(0);

  int cur = 0;
  for (int t = 0; t < ksteps; ++t) {
    bool more1 = (t + 1 < ksteps), more2 = (t + 2 < ksteps);
    if (more1) cvtWriteA(cur ^ 1);
    short8 af[4], bf8[8];
    #pragma unroll
    for (int mi = 0; mi < 4; mi++) {
      int R = wm * 64 + mi * 16 + lrow;
      int p = lko ^ (R & 3);
      af[mi] = *reinterpret_cast<const short8*>((char*)Al[cur] + R * 64 + p * 16);
    }
    #pragma unroll
    for (int ni = 0; ni < 8; ni++) {
      int R = wn * 128 + ni * 16 + lrow;
      int p = lko ^ (R & 3);
      bf8[ni] = *reinterpret_cast<const short8*>((char*)Bl[cur] + R * 64 + p * 16);
    }
    if (more2) loadA_regs(kbase + (t + 2) * 32);
    asm volatile("s_waitcnt lgkmcnt(0)" ::: "memory");
    __builtin_amdgcn_s_barrier();
    __builtin_amdgcn_sched_barrier(0);
    if (more2) stageB(cur, kbase + (t + 2) * 32);
    #pragma unroll
    for (int mi = 0; mi < 4; mi++)
      #pragma unroll
      for (int ni = 0; ni < 8; ni++)
        acc[mi][ni] = __builtin_amdgcn_mfma_f32_16x16x32_bf16(af[mi], bf8[ni], acc[mi][ni], 0, 0, 0);
    if (more1) {
      if (more2) { asm volatile("s_waitcnt vmcnt(6)" ::: "memory"); }
      else       { asm volatile("s_waitcnt vmcnt(0)" ::: "memory"); }
      __builtin_amdgcn_sched_barrier(0);
    }
    cur ^= 1;
  }

  #pragma unroll
  for (int mi = 0; mi < 4; mi++)
    #pragma unroll
    for (int ni = 0; ni < 8; ni++)
      #pragma unroll
      for (int r = 0; r < 4; r++) {
        int row = m0 + wm * 64 + mi * 16 + lko * 4 + r;   // C/D: row=(lane>>4)*4+r
        int col = n0 + wn * 128 + ni * 16 + lrow;         //      col=lane&15
        atomicAdd(&Cacc[(size_t)row * DFC + col], acc[mi][ni][r]);
      }
}

// ---------- layer MFMA GEMM (bf16 A): 128x128 tile, BK=64, dbuf ----------
__global__ __launch_bounds__(256) void gemm_l_k(const unsigned short* __restrict__ A,
    const unsigned short* __restrict__ BT, float* __restrict__ Cacc,
    int K, int Ncols, int tiles_n, int ksteps) {
  __shared__ unsigned short Al[2][128 * 64];
  __shared__ unsigned short Bl[2][128 * 64];
  int tid = threadIdx.x;
  int m0 = (blockIdx.x / tiles_n) * 128;
  int n0 = (blockIdx.x % tiles_n) * 128;
  int kbase = blockIdx.y * ksteps * 64;
  int wid = tid >> 6, lane = tid & 63;
  int wm = wid >> 1, wn = wid & 1;
  int lrow = lane & 15, lko = lane >> 4;

  f32x4 acc[4][4];
  #pragma unroll
  for (int i = 0; i < 4; i++)
    #pragma unroll
    for (int j = 0; j < 4; j++) acc[i][j] = (f32x4){0.f, 0.f, 0.f, 0.f};

  auto stage = [&](unsigned short (*L)[128 * 64], const unsigned short* G, int buf, int k0) {
    #pragma unroll
    for (int j = 0; j < 4; j++) {
      int chb = j * 256 + wid * 64;
      int ch = chb + lane;
      int r = ch >> 3, c = (ch & 7) ^ (r & 7);
      load_lds16(G + (size_t)r * K + k0 + c * 8, (char*)L[buf] + chb * 16);
    }
  };

  stage(Al, A + (size_t)m0 * K, 0, kbase);
  stage(Bl, BT + (size_t)n0 * K, 0, kbase);
  __syncthreads();

  int cur = 0;
  for (int t = 0; t < ksteps; ++t) {
    bool more = (t + 1 < ksteps);
    if (more) {
      stage(Al, A + (size_t)m0 * K, cur ^ 1, kbase + (t + 1) * 64);
      stage(Bl, BT + (size_t)n0 * K, cur ^ 1, kbase + (t + 1) * 64);
    }
    #pragma unroll
    for (int kk = 0; kk < 2; kk++) {
      short8 af[4], bfv[4];
      #pragma unroll
      for (int mi = 0; mi < 4; mi++) {
        int R = wm * 64 + mi * 16 + lrow;
        int slot = ((kk << 2) | lko) ^ (lrow & 7);
        af[mi] = *reinterpret_cast<const short8*>((char*)Al[cur] + R * 128 + slot * 16);
      }
      #pragma unroll
      for (int ni = 0; ni < 4; ni++) {
        int R = wn * 64 + ni * 16 + lrow;
        int slot = ((kk << 2) | lko) ^ (lrow & 7);
        bfv[ni] = *reinterpret_cast<const short8*>((char*)Bl[cur] + R * 128 + slot * 16);
      }
      #pragma unroll
      for (int mi = 0; mi < 4; mi++)
        #pragma unroll
        for (int ni = 0; ni < 4; ni++)
          acc[mi][ni] = __builtin_amdgcn_mfma_f32_16x16x32_bf16(af[mi], bfv[ni], acc[mi][ni], 0, 0, 0);
    }
    __syncthreads();
    cur ^= 1;
  }
  #pragma unroll
  for (int mi = 0; mi < 4; mi++)
    #pragma unroll
    for (int ni = 0; ni < 4; ni++)
      #pragma unroll
      for (int r = 0; r < 4; r++) {
        int row = m0 + wm * 64 + mi * 16 + lko * 4 + r;
        int col = n0 + wn * 64 + ni * 16 + lrow;
        atomicAdd(&Cacc[(size_t)row * Ncols + col], acc[mi][ni][r]);
      }
}

// ---------- feats finalize: +bias -> fp32 out + bf16 copy ----------
__global__ void feats_fin_k(const float* __restrict__ facc, const float* __restrict__ bfc,
                            float* __restrict__ outf, unsigned short* __restrict__ outbf) {
  int i = blockIdx.y;
  int n = blockIdx.x * 256 + threadIdx.x;
  float v = facc[(size_t)i * DFC + n] + bfc[n];
  outf[(size_t)i * DFC + n] = v;
  outbf[(size_t)i * DFC + n] = bfbits(v);
}

__global__ void seg_sum_reduce_k(const float* __restrict__ sxp, float* __restrict__ sx) {
  int k4 = blockIdx.x * 256 + threadIdx.x;
  if (k4 >= FEAT / 4) return;
  int k = k4 * 4;
  int c = blockIdx.y;
  double s0 = 0, s1 = 0, s2 = 0, s3 = 0;
  #pragma unroll
  for (int p = 0; p < 16; p++) {
    float4 v = *reinterpret_cast<const float4*>(sxp + ((size_t)p * 4 + c) * FEAT + k);
    s0 += (double)v.x; s1 += (double)v.y; s2 += (double)v.z; s3 += (double)v.w;
  }
  float4 r; r.x = (float)s0; r.y = (float)s1; r.z = (float)s2; r.w = (float)s3;
  *reinterpret_cast<float4*>(sx + (size_t)c * FEAT + k) = r;
}

__global__ void count_src_k(const int* __restrict__ slab, int* __restrict__ cnt) {
  __shared__ int c[4];
  if (threadIdx.x < 4) c[threadIdx.x] = 0;
  __syncthreads();
  for (int i = threadIdx.x; i < SLEN; i += 256) atomicAdd(&c[slab[i]], 1);
  __syncthreads();
  if (threadIdx.x < 4) cnt[threadIdx.x] = c[threadIdx.x];
}

__global__ void centers_part_k(const float* __restrict__ sx, const float* __restrict__ W,
                               double* __restrict__ cpart) {
  int n = blockIdx.x * 64 + (threadIdx.x & 63);
  int cc = threadIdx.x >> 6;
  int kb = blockIdx.y * (FEAT / CSPLIT), ke = kb + FEAT / CSPLIT;
  const float* sr = sx + (size_t)cc * FEAT;
  double acc = 0.0;
  #pragma unroll 4
  for (int k = kb; k < ke; k++)
    acc += (double)sr[k] * (double)W[(size_t)k * DFC + n];
  cpart[((size_t)blockIdx.y * 4 + cc) * DFC + n] = acc;
}

__global__ void centers_reduce_k(const double* __restrict__ cpart, const float* __restrict__ bfc,
                                 const int* __restrict__ cntsrc, float* __restrict__ Cent) {
  int idx = blockIdx.x * 256 + threadIdx.x;
  int cc = idx >> 9, n = idx & 511;
  double s = 0.0;
  #pragma unroll 4
  for (int p = 0; p < CSPLIT; p++) s += cpart[((size_t)p * 4 + cc) * DFC + n];
  Cent[idx] = (float)(s + (double)cntsrc[cc] * (double)bfc[n]);
}

__global__ void wc_k(const float* __restrict__ W, const float* __restrict__ Cent,
                     float* __restrict__ wc) {
  __shared__ float cs[4 * DFC];
  for (int i = threadIdx.x; i < 4 * DFC; i += 256) cs[i] = Cent[i];
  __syncthreads();
  int k = blockIdx.x * 256 + threadIdx.x;
  if (k >= FEAT) return;
  const float* wr = W + (size_t)k * DFC;
  double a0 = 0, a1 = 0, a2 = 0, a3 = 0;
  #pragma unroll 2
  for (int n = 0; n < DFC; n += 4) {
    float4 w4 = *reinterpret_cast<const float4*>(wr + n);
    a0 += (double)w4.x * cs[0 * DFC + n] + (double)w4.y * cs[0 * DFC + n + 1]
        + (double)w4.z * cs[0 * DFC + n + 2] + (double)w4.w * cs[0 * DFC + n + 3];
    a1 += (double)w4.x * cs[1 * DFC + n] + (double)w4.y * cs[1 * DFC + n + 1]
        + (double)w4.z * cs[1 * DFC + n + 2] + (double)w4.w * cs[1 * DFC + n + 3];
    a2 += (double)w4.x * cs[2 * DFC + n] + (double)w4.y * cs[2 * DFC + n + 1]
        + (double)w4.z * cs[2 * DFC + n + 2] + (double)w4.w * cs[2 * DFC + n + 3];
    a3 += (double)w4.x * cs[3 * DFC + n] + (double)w4.y * cs[3 * DFC + n + 1]
        + (double)w4.z * cs[3 * DFC + n + 2] + (double)w4.w * cs[3 * DFC + n + 3];
  }
  float4 r; r.x = (float)a0; r.y = (float)a1; r.z = (float)a2; r.w = (float)a3;
  *reinterpret_cast<float4*>(wc + 4 * (size_t)k) = r;
}

__global__ void kj_k(const float* __restrict__ Cent, const float* __restrict__ bfc,
                     float* __restrict__ Kj) {
  int j = threadIdx.x >> 6, lane = threadIdx.x & 63;
  float cn = 0.f, bc = 0.f;
  for (int n = lane; n < DFC; n += 64) {
    float c = Cent[j * DFC + n];
    cn += c * c; bc += bfc[n] * c;
  }
  #pragma unroll
  for (int m = 32; m >= 1; m >>= 1) { cn += __shfl_xor(cn, m); bc += __shfl_xor(bc, m); }
  if (lane == 0) Kj[j] = cn - 2.f * bc;
}

__global__ void d2_labels_k(const float* __restrict__ x, const float* __restrict__ wc,
                            const float* __restrict__ Kj, int* __restrict__ tlab) {
  int row = blockIdx.x;
  int tid = threadIdx.x;
  const float* xr = x + (size_t)(SLEN + row) * FEAT;
  double a0 = 0, a1 = 0, a2 = 0, a3 = 0;
  #pragma unroll 2
  for (int k = tid; k < FEAT; k += 256) {
    float xv = xr[k];
    float4 w4 = *reinterpret_cast<const float4*>(wc + 4 * (size_t)k);
    a0 += (double)xv * w4.x; a1 += (double)xv * w4.y;
    a2 += (double)xv * w4.z; a3 += (double)xv * w4.w;
  }
  #pragma unroll
  for (int m = 32; m >= 1; m >>= 1) {
    a0 += __shfl_xor(a0, m); a1 += __shfl_xor(a1, m);
    a2 += __shfl_xor(a2, m); a3 += __shfl_xor(a3, m);
  }
  __shared__ double s[4][4];
  int wid = tid >> 6, lane = tid & 63;
  if (lane == 0) { s[wid][0] = a0; s[wid][1] = a1; s[wid][2] = a2; s[wid][3] = a3; }
  __syncthreads();
  if (tid == 0) {
    double t0 = s[0][0] + s[1][0] + s[2][0] + s[3][0];
    double t1 = s[0][1] + s[1][1] + s[2][1] + s[3][1];
    double t2 = s[0][2] + s[1][2] + s[2][2] + s[3][2];
    double t3 = s[0][3] + s[1][3] + s[2][3] + s[3][3];
    double s0 = (double)Kj[0] - 2.0 * t0;
    double s1 = (double)Kj[1] - 2.0 * t1;
    double s2 = (double)Kj[2] - 2.0 * t2;
    double s3 = (double)Kj[3] - 2.0 * t3;
    int bi = 0; double b = s0;
    if (s1 < b) { b = s1; bi = 1; }
    if (s2 < b) { b = s2; bi = 2; }
    if (s3 < b) { b = s3; bi = 3; }
    tlab[row] = bi;
  }
}

__global__ void finalize_labels_k(const int* __restrict__ slab, const int* __restrict__ tlab,
                                  const int* __restrict__ cntsrc, int* __restrict__ alllab,
                                  float* __restrict__ dinv) {
  __shared__ int ct[4];
  if (threadIdx.x < 4) ct[threadIdx.x] = 0;
  __syncthreads();
  for (int i = threadIdx.x; i < SLEN; i += 256) atomicAdd(&ct[tlab[i]], 1);
  __syncthreads();
  for (int i = threadIdx.x; i < NROWS; i += 256) {
    int lab = (i < SLEN) ? slab[i] : tlab[i - SLEN];
    alllab[i] = lab;
    float rs = (i < SLEN) ? (2.f + (float)ct[lab])
                          : (1.f + (float)cntsrc[lab] + (float)ct[lab]);
    dinv[i] = 1.f / sqrtf(rs);
  }
}

// ---------- A_norm dense write (float4) ----------
__global__ void anorm_k(const int* __restrict__ alllab, const float* __restrict__ dinv,
                        float* __restrict__ Aout) {
  int i = blockIdx.y;
  int j0 = (blockIdx.x * 256 + threadIdx.x) * 4;
  int li = alllab[i];
  float di = dinv[i];
  int4 lj = *reinterpret_cast<const int4*>(alllab + j0);
  float4 dj = *reinterpret_cast<const float4*>(dinv + j0);
  int jj[4] = {lj.x, lj.y, lj.z, lj.w};
  float dd[4] = {dj.x, dj.y, dj.z, dj.w};
  float4 o;
  float* op = &o.x;
  #pragma unroll
  for (int e = 0; e < 4; e++) {
    int j = j0 + e;
    float v;
    if (i == j) v = 2.f * di * dd[e];
    else if (i < SLEN && j < SLEN) v = 0.f;
    else v = (li == jj[e]) ? di * dd[e] : 0.f;
    op[e] = v;
  }
  *reinterpret_cast<float4*>(Aout + (size_t)i * NROWS + j0) = o;
}

// ---------- propagation ----------
__global__ void reduce_st_k(const float* __restrict__ Xacc, const int* __restrict__ alllab,
                            const float* __restrict__ dinv, float* __restrict__ ST, int D) {
  int n = blockIdx.x * 256 + threadIdx.x;
  int i0 = blockIdx.y * 32, i1 = i0 + 32;
  float s[4] = {0, 0, 0, 0}, tt[4] = {0, 0, 0, 0};
  for (int i = i0; i < i1; ++i) {
    float v = dinv[i] * Xacc[(size_t)i * D + n];
    int lab = alllab[i];
    bool src = i < SLEN;
    #pragma unroll
    for (int c = 0; c < 4; c++) {
      s[c]  += (src && lab == c) ? v : 0.f;
      tt[c] += (!src && lab == c) ? v : 0.f;
    }
  }
  #pragma unroll
  for (int c = 0; c < 4; c++) {
    atomicAdd(&ST[c * D + n], s[c]);
    atomicAdd(&ST[(4 + c) * D + n], tt[c]);
  }
}

__global__ void apply_prop_k(const float* __restrict__ Xacc, const float* __restrict__ ST,
                             const int* __restrict__ alllab, const float* __restrict__ dinv,
                             const float* __restrict__ bias, float* __restrict__ outf,
                             unsigned short* __restrict__ outbf, int D) {
  int i = blockIdx.y;
  int n = blockIdx.x * 256 + threadIdx.x;
  float dv = dinv[i];
  int lab = alllab[i];
  float xv = Xacc[(size_t)i * D + n];
  float z;
  if (i < SLEN) z = dv * (2.f * dv * xv + ST[(4 + lab) * D + n]);
  else          z = dv * (ST[lab * D + n] + ST[(4 + lab) * D + n] + dv * xv);
  z += bias[n];
  z = fmaxf(z, 0.f);
  if (outf)  outf[(size_t)i * D + n] = z;
  if (outbf) outbf[(size_t)i * D + n] = bfbits(z);
}

extern "C" void kernel_launch(void* const* d_in, const int* in_sizes, int n_in,
                              void* d_out, int out_size, void* d_ws, size_t ws_size,
                              hipStream_t stream) {
  const float* x    = (const float*)d_in[0];
  const float* Wfc  = (const float*)d_in[1];
  const float* bfc  = (const float*)d_in[2];
  const float* Wg1  = (const float*)d_in[3];
  const float* bg1  = (const float*)d_in[4];
  const float* Wg2  = (const float*)d_in[5];
  const float* bg2  = (const float*)d_in[6];
  const int*   slab = (const int*)d_in[7];

  float* out = (float*)d_out;
  float* out_h = out;                       // 2048*256
  float* out_A = out + 524288;              // 2048*2048
  float* out_f = out + 4718592;             // 2048*512

  char* w = (char*)d_ws;
  unsigned short* wT   = (unsigned short*)(w);
  unsigned short* g1T  = (unsigned short*)(w + 25690112);
  unsigned short* g2T  = (unsigned short*)(w + 26214400);
  float* facc          = (float*)(w + 26476544);
  unsigned short* fbf  = (unsigned short*)(w + 30670848);
  float* x1acc         = (float*)(w + 32768000);
  unsigned short* h1bf = (unsigned short*)(w + 36962304);
  float* x2acc         = (float*)(w + 39059456);
  float* sx            = (float*)(w + 41156608);
  float* Cent          = (float*)(w + 41623552);
  float* wc            = (float*)(w + 41631744);
  float* Kj            = (float*)(w + 42033152);
  int*   tlab          = (int*)(w + 42033216);
  int*   alllab        = (int*)(w + 42037312);
  float* dinv          = (float*)(w + 42045504);
  int*   cntsrc        = (int*)(w + 42053696);
  float* ST1           = (float*)(w + 42053760);
  float* ST2           = (float*)(w + 42070144);

  // aliased scratch (regions dead during the label phase)
  float*  sxp     = (float*)(w + 32768000);   // alias x1acc (+h1bf head), 6.42 MB
  double* cpart_d = (double*)(w + 39059456);  // alias x2acc, 2 MB

  hipMemsetAsync(facc,  0, (size_t)NROWS * DFC * 4, stream);
  hipMemsetAsync(ST1,   0, 8 * DG1 * 4, stream);
  hipMemsetAsync(ST2,   0, 8 * DG2 * 4, stream);

  // weight transposes + bf16 convert
  transpose_cvt_k<<<dim3(FEAT / 64, DFC / 64), 256, 0, stream>>>(Wfc, wT, FEAT, DFC);
  transpose_cvt_k<<<dim3(DFC / 64, DG1 / 64), 256, 0, stream>>>(Wg1, g1T, DFC, DG1);
  transpose_cvt_k<<<dim3(DG1 / 64, DG2 / 64), 256, 0, stream>>>(Wg2, g2T, DG1, DG2);

  // FUSED: FC GEMM (y<16, splitK 16 x 49 steps) + seg_sum_part (y in 16..28)
  gemm_fc_k<<<dim3(16, 16 + 13), 512, 0, stream>>>(x, wT, facc, 49, slab, sxp);
  feats_fin_k<<<dim3(DFC / 256, NROWS), 256, 0, stream>>>(facc, bfc, out_f, fbf);

  // exact label path (sxp already produced by the fused launch)
  seg_sum_reduce_k<<<dim3(25, 4), 256, 0, stream>>>(sxp, sx);
  count_src_k<<<1, 256, 0, stream>>>(slab, cntsrc);
  centers_part_k<<<dim3(DFC / 64, CSPLIT), 256, 0, stream>>>(sx, Wfc, cpart_d);
  centers_reduce_k<<<dim3(4 * DFC / 256), 256, 0, stream>>>(cpart_d, bfc, cntsrc, Cent);
  wc_k<<<dim3(FEAT / 256), 256, 0, stream>>>(Wfc, Cent, wc);
  kj_k<<<1, 256, 0, stream>>>(Cent, bfc, Kj);
  d2_labels_k<<<dim3(NROWS - SLEN), 256, 0, stream>>>(x, wc, Kj, tlab);
  finalize_labels_k<<<1, 256, 0, stream>>>(slab, tlab, cntsrc, alllab, dinv);

  // A_norm dense output
  anorm_k<<<dim3(NROWS / 1024, NROWS), 256, 0, stream>>>(alllab, dinv, out_A);

  // GCN layer 1
  hipMemsetAsync(x1acc, 0, (size_t)NROWS * DG1 * 4, stream);
  gemm_l_k<<<dim3(16 * 4, 4), 256, 0, stream>>>(fbf, g1T, x1acc, DFC, DG1, 4, 2);
  reduce_st_k<<<dim3(DG1 / 256, 64), 256, 0, stream>>>(x1acc, alllab, dinv, ST1, DG1);
  apply_prop_k<<<dim3(DG1 / 256, NROWS), 256, 0, stream>>>(x1acc, ST1, alllab, dinv, bg1,
                                                           nullptr, h1bf, DG1);

  // GCN layer 2
  hipMemsetAsync(x2acc, 0, (size_t)NROWS * DG2 * 4, stream);
  gemm_l_k<<<dim3(16 * 2, 8), 256, 0, stream>>>(h1bf, g2T, x2acc, DG1, DG2, 2, 1);
  reduce_st_k<<<dim3(DG2 / 256, 64), 256, 0, stream>>>(x2acc, alllab, dinv, ST2, DG2);
  apply_prop_k<<<dim3(DG2 / 256, NROWS), 256, 0, stream>>>(x2acc, ST2, alllab, dinv, bg2,
                                                           out_h, nullptr, DG2);

  (void)in_sizes; (void)n_in; (void)out_size; (void)ws_size;
}